// Round 12
// baseline (463.803 us; speedup 1.0000x reference)
//
#include <hip/hip_runtime.h>
#include <hip/hip_bf16.h>

typedef unsigned short u16;
typedef __attribute__((ext_vector_type(8))) short bf16x8;
typedef __attribute__((ext_vector_type(4))) float f32x4;

#define S_LEN  2048
#define DMODEL 1024
#define NHEAD  16
#define DH     64
#define BATCH  4
#define QBLK   128
#define KBLK   64
// XOR-swizzle of 16B chunks within a row (chunk index c, row r)
#define SWZ(row, c) (((c) ^ ((row) & 7)))

__device__ inline u16 f2bf(float f) {
  union { float f; unsigned u; } v; v.f = f;
  unsigned u = v.u;
  return (u16)((u + 0x7FFFu + ((u >> 16) & 1u)) >> 16);
}

__device__ inline f32x4 mfma16(bf16x8 a, bf16x8 b, f32x4 c) {
  return __builtin_amdgcn_mfma_f32_16x16x32_bf16(a, b, c, 0, 0, 0);
}

__device__ inline void gload_lds16(const u16* g, u16* l) {
  __builtin_amdgcn_global_load_lds(
      (const __attribute__((address_space(1))) void*)g,
      (__attribute__((address_space(3))) void*)l, 16, 0, 0);
}

// ---------------- merged prep: x fp32->bf16 convert + 4 weight transposes ----------------
__global__ __launch_bounds__(256) void k_prep(const float* __restrict__ x,
                                              u16* __restrict__ xb,
                                              const float* __restrict__ W0,
                                              const float* __restrict__ W1,
                                              const float* __restrict__ W2,
                                              const float* __restrict__ W3,
                                              u16* __restrict__ WtBase) {
  __shared__ float T[32][33];
  int blk = blockIdx.x, tid = threadIdx.x;
  if (blk < 4096) {
    int idx = blk * 256 + tid;
    const float4* p = (const float4*)(x + (size_t)idx * 8);
    float4 a = p[0], b = p[1];
    bf16x8 o;
    o[0] = (short)f2bf(a.x); o[1] = (short)f2bf(a.y);
    o[2] = (short)f2bf(a.z); o[3] = (short)f2bf(a.w);
    o[4] = (short)f2bf(b.x); o[5] = (short)f2bf(b.y);
    o[6] = (short)f2bf(b.z); o[7] = (short)f2bf(b.w);
    *(bf16x8*)(xb + (size_t)idx * 8) = o;
    return;
  }
  int zi = blk - 4096;
  int z = zi >> 10, rem = zi & 1023;
  const float* W = (z == 0) ? W0 : (z == 1) ? W1 : (z == 2) ? W2 : W3;
  u16* Wt = WtBase + (size_t)z * DMODEL * DMODEL;
  int tx = tid & 31, ty = tid >> 5;             // 32 x 8
  int n0 = (rem & 31) * 32, k0 = (rem >> 5) * 32;
  for (int i = 0; i < 4; ++i)
    T[ty + i * 8][tx] = W[(size_t)(k0 + ty + i * 8) * DMODEL + n0 + tx];
  __syncthreads();
  for (int i = 0; i < 4; ++i)
    Wt[(size_t)(n0 + ty + i * 8) * DMODEL + k0 + tx] = f2bf(T[tx][ty + i * 8]);
}

// ---------------- GEMM inner: 128x128 tile, BK=64 (half the barriers of BK=32) ----------------
// LDS tiles are [128][64] u16 with the 16B-chunk XOR swizzle (SWZ) applied via
// pre-swizzled GLOBAL source + swizzled fragment reads (linear gload_lds dest,
// rule: both-sides-or-neither). 32 MFMA per barrier-pair.
#define GEMM_K64_LOOP(Ablk, Bblk)                                              \
  for (int ks = 0; ks < 16; ++ks) {                                            \
    int k0 = ks * 64;                                                          \
    __syncthreads();                                                           \
    for (int r = 0; r < 4; ++r) {                                              \
      int c = r * 256 + tid;                                                   \
      int row = c >> 3, c8 = c & 7;                                            \
      gload_lds16(Ablk + (size_t)row * K + k0 + SWZ(row, c8) * 8, &As[c * 8]); \
      gload_lds16(Bblk + (size_t)row * K + k0 + SWZ(row, c8) * 8, &Bs[c * 8]); \
    }                                                                          \
    __syncthreads();                                                           \
    for (int kk = 0; kk < 2; ++kk) {                                           \
      bf16x8 af[4], bfr[4];                                                    \
      for (int mt = 0; mt < 4; ++mt) {                                         \
        int row = wr * 64 + mt * 16 + (l & 15);                                \
        af[mt] = *(const bf16x8*)&As[row * 64 + SWZ(row, kk * 4 + (l >> 4)) * 8]; \
      }                                                                        \
      for (int nt = 0; nt < 4; ++nt) {                                         \
        int row = wc * 64 + nt * 16 + (l & 15);                                \
        bfr[nt] = *(const bf16x8*)&Bs[row * 64 + SWZ(row, kk * 4 + (l >> 4)) * 8]; \
      }                                                                        \
      for (int mt = 0; mt < 4; ++mt)                                           \
        for (int nt = 0; nt < 4; ++nt)                                         \
          acc[mt][nt] = mfma16(af[mt], bfr[nt], acc[mt][nt]);                  \
    }                                                                          \
  }

// ---------------- fused QKV GEMM: [8192 x 3072] = A[8192][1024] @ Wcat[3072][1024]^T ----------------
// Supertile XCD mapping (R5). V region writes Vt TRANSPOSED via LDS. Q region
// stores Q PRESCALED by 0.125*log2(e) (scores leave QK^T in exp2 domain).
__global__ __launch_bounds__(256) void k_gemm_qkv(const u16* __restrict__ A,
                                                  const u16* __restrict__ Wcat,
                                                  const float* __restrict__ bq,
                                                  const float* __restrict__ bk,
                                                  const float* __restrict__ bv,
                                                  u16* __restrict__ Qh,
                                                  u16* __restrict__ Kh,
                                                  u16* __restrict__ Vt) {
  const int K = 1024;
  __shared__ u16 As[128 * 64];         // 16 KB
  __shared__ u16 Bs[128 * 64];         // 16 KB
  __shared__ u16 Ts[128 * 64];         // 16 KB transpose staging (V region only)
  int tid = threadIdx.x, w = tid >> 6, l = tid & 63;
  int f = blockIdx.x;                  // 1536 flat
  int xcd = f & 7, i = f >> 3;         // 192 blocks per XCD
  int sb = i >> 6;                     // bn-super 0..2 (Q, K, V)
  int t = i & 63;                      // 64 blocks per supertile
  int bm = xcd * 8 + (t & 7);          // 0..63
  int bn = sb * 8 + (t >> 3);          // 0..23
  int wr = w >> 1, wc = w & 1;
  f32x4 acc[4][4];
  for (int ii = 0; ii < 4; ++ii)
    for (int j = 0; j < 4; ++j) acc[ii][j] = (f32x4){0.f, 0.f, 0.f, 0.f};
  const u16* Ablk = A + (size_t)bm * 128 * K;
  const u16* Bblk = Wcat + (size_t)bn * 128 * K;

  GEMM_K64_LOOP(Ablk, Bblk)

  int region = (bn * 128) >> 10;          // block fully inside one region (uniform)

  if (region != 2) {
    const float* bias = (region == 0) ? bq : bk;
    u16* dst = (region == 0) ? Qh : Kh;
    const float qscale = (region == 0) ? 0.18033688011112042f : 1.0f; // 0.125*log2(e)
    for (int mt = 0; mt < 4; ++mt)
      for (int nt = 0; nt < 4; ++nt) {
        int colg = bn * 128 + wc * 64 + nt * 16 + (l & 15);
        int col = colg & 1023;
        float bsv = bias[col];
        for (int r = 0; r < 4; ++r) {
          int row = bm * 128 + wr * 64 + mt * 16 + (l >> 4) * 4 + r;
          float v = (acc[mt][nt][r] + bsv) * qscale;
          int b = row >> 11, s = row & 2047, h = col >> 6, d = col & 63;
          dst[(((size_t)(b * NHEAD + h)) * S_LEN + s) * DH + d] = f2bf(v);
        }
      }
  } else {
    // V region: transpose per 64-col half via LDS, write Vt [BH][DH][S].
    int hbase = (bn - 16) * 2;
    int b = bm >> 4, s0 = (bm & 15) * 128;
    for (int half = 0; half < 2; ++half) {
      __syncthreads();
      if (wc == half) {
        for (int mt = 0; mt < 4; ++mt)
          for (int nt = 0; nt < 4; ++nt) {
            int cl = nt * 16 + (l & 15);               // 0..63 == d
            float bsv = bv[(hbase + half) * 64 + cl];
            for (int r = 0; r < 4; ++r) {
              int rl = wr * 64 + mt * 16 + (l >> 4) * 4 + r;   // 0..127 == s_local
              Ts[rl * 64 + cl] = f2bf(acc[mt][nt][r] + bsv);
            }
          }
      }
      __syncthreads();
      int d = tid >> 2, seg = tid & 3;
      int h = hbase + half;
      u16* dst = Vt + (((size_t)(b * NHEAD + h)) * DH + d) * S_LEN + s0 + seg * 32;
      bf16x8 o0, o1, o2, o3;
      for (int k = 0; k < 8; ++k) o0[k] = (short)Ts[(seg * 32 + k) * 64 + d];
      for (int k = 0; k < 8; ++k) o1[k] = (short)Ts[(seg * 32 + 8 + k) * 64 + d];
      for (int k = 0; k < 8; ++k) o2[k] = (short)Ts[(seg * 32 + 16 + k) * 64 + d];
      for (int k = 0; k < 8; ++k) o3[k] = (short)Ts[(seg * 32 + 24 + k) * 64 + d];
      *(bf16x8*)dst = o0;
      *(bf16x8*)(dst + 8) = o1;
      *(bf16x8*)(dst + 16) = o2;
      *(bf16x8*)(dst + 24) = o3;
    }
  }
}

// ---------------- out-proj GEMM: C[8192][1024] f32 = ctx[8192][1024] @ WoT^T + bo ----------------
__global__ __launch_bounds__(256) void k_gemm_out(const u16* __restrict__ A,
                                                  const u16* __restrict__ Bt,
                                                  const float* __restrict__ bias,
                                                  float* __restrict__ Cout) {
  const int K = 1024, N = 1024;
  __shared__ u16 As[128 * 64];
  __shared__ u16 Bs[128 * 64];
  int tid = threadIdx.x, w = tid >> 6, l = tid & 63;
  int f = blockIdx.x;                  // 512 flat
  int xcd = f & 7, i = f >> 3;         // 64 blocks per XCD
  int bm = xcd * 8 + (i & 7);          // 0..63
  int bn = i >> 3;                     // 0..7
  int wr = w >> 1, wc = w & 1;
  f32x4 acc[4][4];
  for (int ii = 0; ii < 4; ++ii)
    for (int j = 0; j < 4; ++j) acc[ii][j] = (f32x4){0.f, 0.f, 0.f, 0.f};
  const u16* Ablk = A + (size_t)bm * 128 * K;
  const u16* Bblk = Bt + (size_t)bn * 128 * K;

  GEMM_K64_LOOP(Ablk, Bblk)

  for (int mt = 0; mt < 4; ++mt)
    for (int nt = 0; nt < 4; ++nt) {
      int col = bn * 128 + wc * 64 + nt * 16 + (l & 15);
      float bsv = bias[col];
      for (int r = 0; r < 4; ++r) {
        int row = bm * 128 + wr * 64 + mt * 16 + (l >> 4) * 4 + r;
        Cout[(size_t)row * N + col] = acc[mt][nt][r] + bsv;
      }
    }
}

// ---------------- fused causal attention (R11 + heavy/light ALTERNATING dispatch) ----------------
// (1) Store-drain decoupling: pass 2 double-buffers K fragments ACROSS tiles.
// (2) XCD L2 locality: each XCD owns 8 whole heads.
// (3) Deferred pass-1 reduce (R9: -40us); prescaled Q + log-domain norm (R10);
//     setprio around MFMA clusters (R11).
// (4) NEW: per-block P-write volume is UNIFORM (1MB: causal+zero complement),
//     but compute scales with qb. Heavy-first order created two regimes:
//     all-heavy (write pipe idle) then all-light (compute idle). ALTERNATING
//     order 15,0,14,1,... makes each CU host ~one compute-bound and ~one
//     write-bound block concurrently -> both pipes saturated throughout.
//     (R7's pairing failed because it SERIALIZED the pair inside one block;
//     this keeps them as separate co-resident blocks.)
// Fixed-shift softmax (|x| small), zero barriers anywhere.

#define LOADK(KF, J0)                                                          \
  for (int kk_ = 0; kk_ < 2; ++kk_)                                            \
    for (int nt_ = 0; nt_ < 4; ++nt_)                                          \
      KF[kk_][nt_] = *(const bf16x8*)(Kg + (size_t)((J0) + nt_ * 16 + ln) * DH \
                                      + kk_ * 32 + lg * 8);

#define P1TILE(KF, J0)                                                         \
  {                                                                            \
    const int j0_ = (J0);                                                      \
    f32x4 acc[2][4];                                                           \
    for (int mt = 0; mt < 2; ++mt)                                             \
      for (int nt = 0; nt < 4; ++nt) acc[mt][nt] = (f32x4){0.f, 0.f, 0.f, 0.f};\
    __builtin_amdgcn_s_setprio(1);                                             \
    for (int kk = 0; kk < 2; ++kk)                                             \
      for (int mt = 0; mt < 2; ++mt)                                           \
        for (int nt = 0; nt < 4; ++nt)                                         \
          acc[mt][nt] = mfma16(qf[mt][kk], KF[kk][nt], acc[mt][nt]);           \
    __builtin_amdgcn_s_setprio(0);                                             \
    bool mask_ = (j0_ >= q0);                                                  \
    for (int mt = 0; mt < 2; ++mt)                                             \
      for (int r = 0; r < 4; ++r) {                                            \
        int rl = w * 32 + mt * 16 + lg * 4 + r;                                \
        float x0 = acc[mt][0][r];                                              \
        float x1 = acc[mt][1][r];                                              \
        float x2 = acc[mt][2][r];                                              \
        float x3 = acc[mt][3][r];                                              \
        if (mask_) {                                                           \
          if (j0_ + 0 + ln > q0 + rl) x0 = -1e9f;                              \
          if (j0_ + 16 + ln > q0 + rl) x1 = -1e9f;                             \
          if (j0_ + 32 + ln > q0 + rl) x2 = -1e9f;                             \
          if (j0_ + 48 + ln > q0 + rl) x3 = -1e9f;                             \
        }                                                                      \
        lrow[mt][r] += (__builtin_amdgcn_exp2f(x0) + __builtin_amdgcn_exp2f(x1)) + \
                       (__builtin_amdgcn_exp2f(x2) + __builtin_amdgcn_exp2f(x3));  \
      }                                                                        \
  }

// Pass-2 tile: QK^T (current K buf) -> prefetch next K buf -> store epilogue -> PV.
#define P2TILE(KFC, KFN, KB, PRE)                                              \
  {                                                                            \
    const int j0_ = (KB) * KBLK;                                               \
    bf16x8 vb_[2][4];                                                          \
    for (int kk = 0; kk < 2; ++kk)                                             \
      for (int nt = 0; nt < 4; ++nt)                                           \
        vb_[kk][nt] = *(const bf16x8*)(Vg + (size_t)(nt * 16 + ln) * S_LEN +   \
                                       j0_ + kk * 32 + lg * 8);                \
    f32x4 acc[2][4];                                                           \
    for (int mt = 0; mt < 2; ++mt)                                             \
      for (int nt = 0; nt < 4; ++nt) acc[mt][nt] = (f32x4){0.f, 0.f, 0.f, 0.f};\
    __builtin_amdgcn_s_setprio(1);                                             \
    for (int kk = 0; kk < 2; ++kk)                                             \
      for (int mt = 0; mt < 2; ++mt)                                           \
        for (int nt = 0; nt < 4; ++nt)                                         \
          acc[mt][nt] = mfma16(qf[mt][kk], KFC[kk][nt], acc[mt][nt]);          \
    __builtin_amdgcn_s_setprio(0);                                             \
    if (PRE) { LOADK(KFN, j0_ + KBLK); }                                       \
    bool mask_ = (j0_ >= q0);                                                  \
    for (int mt = 0; mt < 2; ++mt)                                             \
      for (int r = 0; r < 4; ++r) {                                            \
        int rl = w * 32 + mt * 16 + lg * 4 + r;                                \
        float lgil = lg2il[mt][r];                                             \
        float* prow = Pg + (size_t)(q0 + rl) * S_LEN + j0_;                    \
        for (int nt = 0; nt < 4; ++nt) {                                       \
          int cl = nt * 16 + ln;                                               \
          float v = acc[mt][nt][r];                                            \
          if (mask_ && (j0_ + cl > q0 + rl)) v = -1e9f;                        \
          float p = __builtin_amdgcn_exp2f(v + lgil);                          \
          __builtin_nontemporal_store(p, prow + cl);                           \
          Ps[rl * 64 + SWZ(rl, cl >> 3) * 8 + (cl & 7)] = f2bf(p);             \
        }                                                                      \
      }                                                                        \
    __builtin_amdgcn_s_setprio(1);                                             \
    for (int kk = 0; kk < 2; ++kk) {                                           \
      bf16x8 pa[2];                                                            \
      for (int mt = 0; mt < 2; ++mt) {                                         \
        int row = w * 32 + mt * 16 + ln;                                       \
        pa[mt] = *(const bf16x8*)&Ps[row * 64 + SWZ(row, kk * 4 + lg) * 8];    \
      }                                                                        \
      for (int mt = 0; mt < 2; ++mt)                                           \
        for (int nt = 0; nt < 4; ++nt)                                         \
          octx[mt][nt] = mfma16(pa[mt], vb_[kk][nt], octx[mt][nt]);            \
    }                                                                          \
    __builtin_amdgcn_s_setprio(0);                                             \
  }

__global__ __launch_bounds__(256) void k_attn(const u16* __restrict__ Qh,
                                              const u16* __restrict__ Kh,
                                              const u16* __restrict__ Vt,
                                              float* __restrict__ P,
                                              u16* __restrict__ ctx) {
  __shared__ u16 Ps[QBLK * KBLK];        // 16 KB (bf16 P tile; wave-local rows)

  // XCD-locality swizzle + ALTERNATING heavy/light qb order (15,0,14,1,...):
  // co-resident blocks on a CU are one compute-bound + one write-bound.
  int flat = blockIdx.x;
  int xcd = flat & 7, idx = flat >> 3;           // 128 blocks per XCD
  int bh = xcd * 8 + (idx >> 4);                 // 8 heads per XCD, head-major
  int j = idx & 15;
  int qb = (j & 1) ? (j >> 1) : (15 - (j >> 1)); // 15,0,14,1,13,2,...,8,7
  int q0 = qb * QBLK;
  int tid = threadIdx.x, w = tid >> 6, l = tid & 63;
  const int lg = l >> 4, ln = l & 15;
  const u16* Qg = Qh + (size_t)bh * S_LEN * DH;
  const u16* Kg = Kh + (size_t)bh * S_LEN * DH;
  const u16* Vg = Vt + (size_t)bh * DH * S_LEN;
  float* Pg = P + (size_t)bh * S_LEN * S_LEN;

  // Q fragments in registers (wave-private rows w*32 .. w*32+31)
  bf16x8 qf[2][2];
  for (int mt = 0; mt < 2; ++mt)
    for (int kk = 0; kk < 2; ++kk)
      qf[mt][kk] = *(const bf16x8*)(Qg + (size_t)(q0 + w * 32 + mt * 16 + ln) * DH +
                                    kk * 32 + lg * 8);

  const int nkb = q0 / KBLK + QBLK / KBLK;   // = 2*(qb+1), always even

  float lrow[2][4];
  for (int mt = 0; mt < 2; ++mt)
    for (int r = 0; r < 4; ++r) lrow[mt][r] = 0.f;

  // ---- pass 1: per-lane partial denominators, K double-buffered ----
  {
    bf16x8 kfA[2][4], kfB[2][4];
    LOADK(kfA, 0);
    for (int kb = 0; kb < nkb; kb += 2) {
      LOADK(kfB, (kb + 1) * KBLK);
      P1TILE(kfA, kb * KBLK);
      if (kb + 2 < nkb) LOADK(kfA, (kb + 2) * KBLK);
      P1TILE(kfB, (kb + 1) * KBLK);
    }
  }
  // one cross-lane reduce per row-slot, then move to log2 domain
  float lg2il[2][4];
  for (int mt = 0; mt < 2; ++mt)
    for (int r = 0; r < 4; ++r) {
      float s = lrow[mt][r];
      s += __shfl_xor(s, 1);
      s += __shfl_xor(s, 2);
      s += __shfl_xor(s, 4);
      s += __shfl_xor(s, 8);
      lg2il[mt][r] = -__log2f(s);
    }

  // ---- pass 2: K double-buffered across tiles (loads always older than stores) ----
  f32x4 octx[2][4];
  for (int mt = 0; mt < 2; ++mt)
    for (int nt = 0; nt < 4; ++nt) octx[mt][nt] = (f32x4){0.f, 0.f, 0.f, 0.f};

  {
    bf16x8 kfA[2][4], kfB[2][4];
    LOADK(kfA, 0);
    for (int kb = 0; kb < nkb; kb += 2) {
      P2TILE(kfA, kfB, kb, 1);                       // kb+1 < nkb (nkb even)
      P2TILE(kfB, kfA, kb + 1, (kb + 2) < nkb);
    }
  }

  // zero-fill fully-masked future columns (reference softmax gives exactly 0)
  int jz = nkb * KBLK;
  int ncol4 = (S_LEN - jz) >> 2;
  if (ncol4 > 0) {
    f32x4 z = (f32x4){0.f, 0.f, 0.f, 0.f};
    for (int rr = 0; rr < QBLK; ++rr) {
      float* prow = Pg + (size_t)(q0 + rr) * S_LEN + jz;
      for (int j4 = tid; j4 < ncol4; j4 += 256)
        __builtin_nontemporal_store(z, (f32x4*)(prow + j4 * 4));
    }
  }

  // write context bf16 [8192][1024] (row = b*S+s, col = h*64+d)
  int b = bh >> 4, h = bh & 15;
  for (int mt = 0; mt < 2; ++mt)
    for (int nt = 0; nt < 4; ++nt)
      for (int r = 0; r < 4; ++r) {
        int rl = w * 32 + mt * 16 + lg * 4 + r;
        int d = nt * 16 + ln;
        ctx[((size_t)(b * S_LEN + q0 + rl)) * DMODEL + h * DH + d] =
            f2bf(octx[mt][nt][r]);
      }
}

extern "C" void kernel_launch(void* const* d_in, const int* in_sizes, int n_in,
                              void* d_out, int out_size, void* d_ws, size_t ws_size,
                              hipStream_t stream) {
  (void)in_sizes; (void)n_in; (void)out_size; (void)ws_size;
  const float* x  = (const float*)d_in[0];
  // d_in[1] = attn_mask (static causal; not needed)
  const float* Wq = (const float*)d_in[2];
  const float* bq = (const float*)d_in[3];
  const float* Wk = (const float*)d_in[4];
  const float* bk = (const float*)d_in[5];
  const float* Wv = (const float*)d_in[6];
  const float* bv = (const float*)d_in[7];
  const float* Wo = (const float*)d_in[8];
  const float* bo = (const float*)d_in[9];

  char* ws = (char*)d_ws;
  u16* xb   = (u16*)(ws);                                  // 16 MB
  u16* Wcat = (u16*)(ws + 16777216);                       // WqT|WkT|WvT|WoT, 2 MB each
  u16* WoT  = Wcat + 3 * (size_t)DMODEL * DMODEL;
  u16* Qh   = (u16*)(ws + 25165824);                       // 16 MB each
  u16* Kh   = (u16*)(ws + 25165824 + 1 * 16777216);
  u16* ctx  = (u16*)(ws + 25165824 + 2 * 16777216);
  u16* Vt   = (u16*)(ws + 25165824 + 3 * 16777216);

  float* outp = (float*)d_out;
  float* Pg = outp + (size_t)BATCH * S_LEN * DMODEL;

  k_prep<<<dim3(8192), 256, 0, stream>>>(x, xb, Wq, Wk, Wv, Wo, Wcat);
  k_gemm_qkv<<<dim3(1536), 256, 0, stream>>>(xb, Wcat, bq, bk, bv, Qh, Kh, Vt);
  k_attn<<<dim3(1024), 256, 0, stream>>>(Qh, Kh, Vt, Pg, ctx);
  k_gemm_out<<<dim3(512), 256, 0, stream>>>(ctx, WoT, bo, outp);
}

// Round 13
// 410.838 us; speedup vs baseline: 1.1289x; 1.1289x over previous
//
#include <hip/hip_runtime.h>
#include <hip/hip_bf16.h>

typedef unsigned short u16;
typedef __attribute__((ext_vector_type(8))) short bf16x8;
typedef __attribute__((ext_vector_type(4))) float f32x4;

#define S_LEN  2048
#define DMODEL 1024
#define NHEAD  16
#define DH     64
#define BATCH  4
#define QBLK   128
#define KBLK   64
// XOR-swizzle of 16B chunks within a row (chunk index c, row r)
#define SWZ(row, c) (((c) ^ ((row) & 7)))

__device__ inline u16 f2bf(float f) {
  union { float f; unsigned u; } v; v.f = f;
  unsigned u = v.u;
  return (u16)((u + 0x7FFFu + ((u >> 16) & 1u)) >> 16);
}

__device__ inline f32x4 mfma16(bf16x8 a, bf16x8 b, f32x4 c) {
  return __builtin_amdgcn_mfma_f32_16x16x32_bf16(a, b, c, 0, 0, 0);
}

__device__ inline void gload_lds16(const u16* g, u16* l) {
  __builtin_amdgcn_global_load_lds(
      (const __attribute__((address_space(1))) void*)g,
      (__attribute__((address_space(3))) void*)l, 16, 0, 0);
}

// ---------------- merged prep: x fp32->bf16 convert + 4 weight transposes ----------------
__global__ __launch_bounds__(256) void k_prep(const float* __restrict__ x,
                                              u16* __restrict__ xb,
                                              const float* __restrict__ W0,
                                              const float* __restrict__ W1,
                                              const float* __restrict__ W2,
                                              const float* __restrict__ W3,
                                              u16* __restrict__ WtBase) {
  __shared__ float T[32][33];
  int blk = blockIdx.x, tid = threadIdx.x;
  if (blk < 4096) {
    int idx = blk * 256 + tid;
    const float4* p = (const float4*)(x + (size_t)idx * 8);
    float4 a = p[0], b = p[1];
    bf16x8 o;
    o[0] = (short)f2bf(a.x); o[1] = (short)f2bf(a.y);
    o[2] = (short)f2bf(a.z); o[3] = (short)f2bf(a.w);
    o[4] = (short)f2bf(b.x); o[5] = (short)f2bf(b.y);
    o[6] = (short)f2bf(b.z); o[7] = (short)f2bf(b.w);
    *(bf16x8*)(xb + (size_t)idx * 8) = o;
    return;
  }
  int zi = blk - 4096;
  int z = zi >> 10, rem = zi & 1023;
  const float* W = (z == 0) ? W0 : (z == 1) ? W1 : (z == 2) ? W2 : W3;
  u16* Wt = WtBase + (size_t)z * DMODEL * DMODEL;
  int tx = tid & 31, ty = tid >> 5;             // 32 x 8
  int n0 = (rem & 31) * 32, k0 = (rem >> 5) * 32;
  for (int i = 0; i < 4; ++i)
    T[ty + i * 8][tx] = W[(size_t)(k0 + ty + i * 8) * DMODEL + n0 + tx];
  __syncthreads();
  for (int i = 0; i < 4; ++i)
    Wt[(size_t)(n0 + ty + i * 8) * DMODEL + k0 + tx] = f2bf(T[tx][ty + i * 8]);
}

// ---------------- GEMM inner: 128x128 tile, BK=64 (half the barriers of BK=32) ----------------
// LDS tiles are [128][64] u16 with the 16B-chunk XOR swizzle (SWZ) applied via
// pre-swizzled GLOBAL source + swizzled fragment reads (linear gload_lds dest,
// rule: both-sides-or-neither). 32 MFMA per barrier-pair.
#define GEMM_K64_LOOP(Ablk, Bblk)                                              \
  for (int ks = 0; ks < 16; ++ks) {                                            \
    int k0 = ks * 64;                                                          \
    __syncthreads();                                                           \
    for (int r = 0; r < 4; ++r) {                                              \
      int c = r * 256 + tid;                                                   \
      int row = c >> 3, c8 = c & 7;                                            \
      gload_lds16(Ablk + (size_t)row * K + k0 + SWZ(row, c8) * 8, &As[c * 8]); \
      gload_lds16(Bblk + (size_t)row * K + k0 + SWZ(row, c8) * 8, &Bs[c * 8]); \
    }                                                                          \
    __syncthreads();                                                           \
    for (int kk = 0; kk < 2; ++kk) {                                           \
      bf16x8 af[4], bfr[4];                                                    \
      for (int mt = 0; mt < 4; ++mt) {                                         \
        int row = wr * 64 + mt * 16 + (l & 15);                                \
        af[mt] = *(const bf16x8*)&As[row * 64 + SWZ(row, kk * 4 + (l >> 4)) * 8]; \
      }                                                                        \
      for (int nt = 0; nt < 4; ++nt) {                                         \
        int row = wc * 64 + nt * 16 + (l & 15);                                \
        bfr[nt] = *(const bf16x8*)&Bs[row * 64 + SWZ(row, kk * 4 + (l >> 4)) * 8]; \
      }                                                                        \
      for (int mt = 0; mt < 4; ++mt)                                           \
        for (int nt = 0; nt < 4; ++nt)                                         \
          acc[mt][nt] = mfma16(af[mt], bfr[nt], acc[mt][nt]);                  \
    }                                                                          \
  }

// ---------------- fused QKV GEMM: [8192 x 3072] = A[8192][1024] @ Wcat[3072][1024]^T ----------------
// Supertile XCD mapping (R5). V region writes Vt TRANSPOSED via LDS; the
// transpose staging buffer ALIASES As (dead after the K-loop) so the kernel
// stays at 32 KB LDS (was 48 KB with a separate Ts) -> better occupancy.
// Q region stores Q PRESCALED by 0.125*log2(e) (scores leave QK^T in exp2 domain).
__global__ __launch_bounds__(256) void k_gemm_qkv(const u16* __restrict__ A,
                                                  const u16* __restrict__ Wcat,
                                                  const float* __restrict__ bq,
                                                  const float* __restrict__ bk,
                                                  const float* __restrict__ bv,
                                                  u16* __restrict__ Qh,
                                                  u16* __restrict__ Kh,
                                                  u16* __restrict__ Vt) {
  const int K = 1024;
  __shared__ u16 As[128 * 64];         // 16 KB (reused as V-transpose staging)
  __shared__ u16 Bs[128 * 64];         // 16 KB
  int tid = threadIdx.x, w = tid >> 6, l = tid & 63;
  int f = blockIdx.x;                  // 1536 flat
  int xcd = f & 7, i = f >> 3;         // 192 blocks per XCD
  int sb = i >> 6;                     // bn-super 0..2 (Q, K, V)
  int t = i & 63;                      // 64 blocks per supertile
  int bm = xcd * 8 + (t & 7);          // 0..63
  int bn = sb * 8 + (t >> 3);          // 0..23
  int wr = w >> 1, wc = w & 1;
  f32x4 acc[4][4];
  for (int ii = 0; ii < 4; ++ii)
    for (int j = 0; j < 4; ++j) acc[ii][j] = (f32x4){0.f, 0.f, 0.f, 0.f};
  const u16* Ablk = A + (size_t)bm * 128 * K;
  const u16* Bblk = Wcat + (size_t)bn * 128 * K;

  GEMM_K64_LOOP(Ablk, Bblk)

  int region = (bn * 128) >> 10;          // block fully inside one region (uniform)

  if (region != 2) {
    const float* bias = (region == 0) ? bq : bk;
    u16* dst = (region == 0) ? Qh : Kh;
    const float qscale = (region == 0) ? 0.18033688011112042f : 1.0f; // 0.125*log2(e)
    for (int mt = 0; mt < 4; ++mt)
      for (int nt = 0; nt < 4; ++nt) {
        int colg = bn * 128 + wc * 64 + nt * 16 + (l & 15);
        int col = colg & 1023;
        float bsv = bias[col];
        for (int r = 0; r < 4; ++r) {
          int row = bm * 128 + wr * 64 + mt * 16 + (l >> 4) * 4 + r;
          float v = (acc[mt][nt][r] + bsv) * qscale;
          int b = row >> 11, s = row & 2047, h = col >> 6, d = col & 63;
          dst[(((size_t)(b * NHEAD + h)) * S_LEN + s) * DH + d] = f2bf(v);
        }
      }
  } else {
    // V region: transpose per 64-col half via LDS (staging aliased onto As),
    // write Vt [BH][DH][S]. As is dead after the K-loop; barriers separate uses.
    u16* Ts = As;
    int hbase = (bn - 16) * 2;
    int b = bm >> 4, s0 = (bm & 15) * 128;
    for (int half = 0; half < 2; ++half) {
      __syncthreads();
      if (wc == half) {
        for (int mt = 0; mt < 4; ++mt)
          for (int nt = 0; nt < 4; ++nt) {
            int cl = nt * 16 + (l & 15);               // 0..63 == d
            float bsv = bv[(hbase + half) * 64 + cl];
            for (int r = 0; r < 4; ++r) {
              int rl = wr * 64 + mt * 16 + (l >> 4) * 4 + r;   // 0..127 == s_local
              Ts[rl * 64 + cl] = f2bf(acc[mt][nt][r] + bsv);
            }
          }
      }
      __syncthreads();
      int d = tid >> 2, seg = tid & 3;
      int h = hbase + half;
      u16* dst = Vt + (((size_t)(b * NHEAD + h)) * DH + d) * S_LEN + s0 + seg * 32;
      bf16x8 o0, o1, o2, o3;
      for (int k = 0; k < 8; ++k) o0[k] = (short)Ts[(seg * 32 + k) * 64 + d];
      for (int k = 0; k < 8; ++k) o1[k] = (short)Ts[(seg * 32 + 8 + k) * 64 + d];
      for (int k = 0; k < 8; ++k) o2[k] = (short)Ts[(seg * 32 + 16 + k) * 64 + d];
      for (int k = 0; k < 8; ++k) o3[k] = (short)Ts[(seg * 32 + 24 + k) * 64 + d];
      *(bf16x8*)dst = o0;
      *(bf16x8*)(dst + 8) = o1;
      *(bf16x8*)(dst + 16) = o2;
      *(bf16x8*)(dst + 24) = o3;
    }
  }
}

// ---------------- out-proj GEMM: C[8192][1024] f32 = ctx[8192][1024] @ WoT^T + bo ----------------
__global__ __launch_bounds__(256) void k_gemm_out(const u16* __restrict__ A,
                                                  const u16* __restrict__ Bt,
                                                  const float* __restrict__ bias,
                                                  float* __restrict__ Cout) {
  const int K = 1024, N = 1024;
  __shared__ u16 As[128 * 64];
  __shared__ u16 Bs[128 * 64];
  int tid = threadIdx.x, w = tid >> 6, l = tid & 63;
  int f = blockIdx.x;                  // 512 flat
  int xcd = f & 7, i = f >> 3;         // 64 blocks per XCD
  int bm = xcd * 8 + (i & 7);          // 0..63
  int bn = i >> 3;                     // 0..7
  int wr = w >> 1, wc = w & 1;
  f32x4 acc[4][4];
  for (int ii = 0; ii < 4; ++ii)
    for (int j = 0; j < 4; ++j) acc[ii][j] = (f32x4){0.f, 0.f, 0.f, 0.f};
  const u16* Ablk = A + (size_t)bm * 128 * K;
  const u16* Bblk = Bt + (size_t)bn * 128 * K;

  GEMM_K64_LOOP(Ablk, Bblk)

  for (int mt = 0; mt < 4; ++mt)
    for (int nt = 0; nt < 4; ++nt) {
      int col = bn * 128 + wc * 64 + nt * 16 + (l & 15);
      float bsv = bias[col];
      for (int r = 0; r < 4; ++r) {
        int row = bm * 128 + wr * 64 + mt * 16 + (l >> 4) * 4 + r;
        Cout[(size_t)row * N + col] = acc[mt][nt][r] + bsv;
      }
    }
}

// ---------------- fused causal attention (R11: heavy-first; best-known schedule) ----------------
// (1) Store-drain decoupling: pass 2 double-buffers K fragments ACROSS tiles.
// (2) XCD L2 locality: each XCD owns 8 whole heads.
// (3) HEAVY-FIRST qb order (R6). Both alternatives lost: R7 pairing (-15us,
//     serialization kills backfill) and R12 alternating (-52us, medium-heavy
//     blocks start last -> long tail). Heavy-first descending is the optimal
//     static schedule for this triangular workload at ~2 blocks/CU.
// (4) Deferred pass-1 reduce (R9: -40us); prescaled Q + log-domain norm (R10);
//     setprio around MFMA clusters (R11).
// Fixed-shift softmax (|x| small), zero barriers anywhere.

#define LOADK(KF, J0)                                                          \
  for (int kk_ = 0; kk_ < 2; ++kk_)                                            \
    for (int nt_ = 0; nt_ < 4; ++nt_)                                          \
      KF[kk_][nt_] = *(const bf16x8*)(Kg + (size_t)((J0) + nt_ * 16 + ln) * DH \
                                      + kk_ * 32 + lg * 8);

#define P1TILE(KF, J0)                                                         \
  {                                                                            \
    const int j0_ = (J0);                                                      \
    f32x4 acc[2][4];                                                           \
    for (int mt = 0; mt < 2; ++mt)                                             \
      for (int nt = 0; nt < 4; ++nt) acc[mt][nt] = (f32x4){0.f, 0.f, 0.f, 0.f};\
    __builtin_amdgcn_s_setprio(1);                                             \
    for (int kk = 0; kk < 2; ++kk)                                             \
      for (int mt = 0; mt < 2; ++mt)                                           \
        for (int nt = 0; nt < 4; ++nt)                                         \
          acc[mt][nt] = mfma16(qf[mt][kk], KF[kk][nt], acc[mt][nt]);           \
    __builtin_amdgcn_s_setprio(0);                                             \
    bool mask_ = (j0_ >= q0);                                                  \
    for (int mt = 0; mt < 2; ++mt)                                             \
      for (int r = 0; r < 4; ++r) {                                            \
        int rl = w * 32 + mt * 16 + lg * 4 + r;                                \
        float x0 = acc[mt][0][r];                                              \
        float x1 = acc[mt][1][r];                                              \
        float x2 = acc[mt][2][r];                                              \
        float x3 = acc[mt][3][r];                                              \
        if (mask_) {                                                           \
          if (j0_ + 0 + ln > q0 + rl) x0 = -1e9f;                              \
          if (j0_ + 16 + ln > q0 + rl) x1 = -1e9f;                             \
          if (j0_ + 32 + ln > q0 + rl) x2 = -1e9f;                             \
          if (j0_ + 48 + ln > q0 + rl) x3 = -1e9f;                             \
        }                                                                      \
        lrow[mt][r] += (__builtin_amdgcn_exp2f(x0) + __builtin_amdgcn_exp2f(x1)) + \
                       (__builtin_amdgcn_exp2f(x2) + __builtin_amdgcn_exp2f(x3));  \
      }                                                                        \
  }

// Pass-2 tile: QK^T (current K buf) -> prefetch next K buf -> store epilogue -> PV.
#define P2TILE(KFC, KFN, KB, PRE)                                              \
  {                                                                            \
    const int j0_ = (KB) * KBLK;                                               \
    bf16x8 vb_[2][4];                                                          \
    for (int kk = 0; kk < 2; ++kk)                                             \
      for (int nt = 0; nt < 4; ++nt)                                           \
        vb_[kk][nt] = *(const bf16x8*)(Vg + (size_t)(nt * 16 + ln) * S_LEN +   \
                                       j0_ + kk * 32 + lg * 8);                \
    f32x4 acc[2][4];                                                           \
    for (int mt = 0; mt < 2; ++mt)                                             \
      for (int nt = 0; nt < 4; ++nt) acc[mt][nt] = (f32x4){0.f, 0.f, 0.f, 0.f};\
    __builtin_amdgcn_s_setprio(1);                                             \
    for (int kk = 0; kk < 2; ++kk)                                             \
      for (int mt = 0; mt < 2; ++mt)                                           \
        for (int nt = 0; nt < 4; ++nt)                                         \
          acc[mt][nt] = mfma16(qf[mt][kk], KFC[kk][nt], acc[mt][nt]);          \
    __builtin_amdgcn_s_setprio(0);                                             \
    if (PRE) { LOADK(KFN, j0_ + KBLK); }                                       \
    bool mask_ = (j0_ >= q0);                                                  \
    for (int mt = 0; mt < 2; ++mt)                                             \
      for (int r = 0; r < 4; ++r) {                                            \
        int rl = w * 32 + mt * 16 + lg * 4 + r;                                \
        float lgil = lg2il[mt][r];                                             \
        float* prow = Pg + (size_t)(q0 + rl) * S_LEN + j0_;                    \
        for (int nt = 0; nt < 4; ++nt) {                                       \
          int cl = nt * 16 + ln;                                               \
          float v = acc[mt][nt][r];                                            \
          if (mask_ && (j0_ + cl > q0 + rl)) v = -1e9f;                        \
          float p = __builtin_amdgcn_exp2f(v + lgil);                          \
          __builtin_nontemporal_store(p, prow + cl);                           \
          Ps[rl * 64 + SWZ(rl, cl >> 3) * 8 + (cl & 7)] = f2bf(p);             \
        }                                                                      \
      }                                                                        \
    __builtin_amdgcn_s_setprio(1);                                             \
    for (int kk = 0; kk < 2; ++kk) {                                           \
      bf16x8 pa[2];                                                            \
      for (int mt = 0; mt < 2; ++mt) {                                         \
        int row = w * 32 + mt * 16 + ln;                                       \
        pa[mt] = *(const bf16x8*)&Ps[row * 64 + SWZ(row, kk * 4 + lg) * 8];    \
      }                                                                        \
      for (int mt = 0; mt < 2; ++mt)                                           \
        for (int nt = 0; nt < 4; ++nt)                                         \
          octx[mt][nt] = mfma16(pa[mt], vb_[kk][nt], octx[mt][nt]);            \
    }                                                                          \
    __builtin_amdgcn_s_setprio(0);                                             \
  }

__global__ __launch_bounds__(256) void k_attn(const u16* __restrict__ Qh,
                                              const u16* __restrict__ Kh,
                                              const u16* __restrict__ Vt,
                                              float* __restrict__ P,
                                              u16* __restrict__ ctx) {
  __shared__ u16 Ps[QBLK * KBLK];        // 16 KB (bf16 P tile; wave-local rows)

  // XCD-locality swizzle + heavy-first qb order.
  int flat = blockIdx.x;
  int xcd = flat & 7, idx = flat >> 3;           // 128 blocks per XCD
  int bh = xcd * 8 + (idx >> 4);                 // 8 heads per XCD, head-major
  int qb = 15 - (idx & 15);                      // heavy blocks dispatch first
  int q0 = qb * QBLK;
  int tid = threadIdx.x, w = tid >> 6, l = tid & 63;
  const int lg = l >> 4, ln = l & 15;
  const u16* Qg = Qh + (size_t)bh * S_LEN * DH;
  const u16* Kg = Kh + (size_t)bh * S_LEN * DH;
  const u16* Vg = Vt + (size_t)bh * DH * S_LEN;
  float* Pg = P + (size_t)bh * S_LEN * S_LEN;

  // Q fragments in registers (wave-private rows w*32 .. w*32+31)
  bf16x8 qf[2][2];
  for (int mt = 0; mt < 2; ++mt)
    for (int kk = 0; kk < 2; ++kk)
      qf[mt][kk] = *(const bf16x8*)(Qg + (size_t)(q0 + w * 32 + mt * 16 + ln) * DH +
                                    kk * 32 + lg * 8);

  const int nkb = q0 / KBLK + QBLK / KBLK;   // = 2*(qb+1), always even

  float lrow[2][4];
  for (int mt = 0; mt < 2; ++mt)
    for (int r = 0; r < 4; ++r) lrow[mt][r] = 0.f;

  // ---- pass 1: per-lane partial denominators, K double-buffered ----
  {
    bf16x8 kfA[2][4], kfB[2][4];
    LOADK(kfA, 0);
    for (int kb = 0; kb < nkb; kb += 2) {
      LOADK(kfB, (kb + 1) * KBLK);
      P1TILE(kfA, kb * KBLK);
      if (kb + 2 < nkb) LOADK(kfA, (kb + 2) * KBLK);
      P1TILE(kfB, (kb + 1) * KBLK);
    }
  }
  // one cross-lane reduce per row-slot, then move to log2 domain
  float lg2il[2][4];
  for (int mt = 0; mt < 2; ++mt)
    for (int r = 0; r < 4; ++r) {
      float s = lrow[mt][r];
      s += __shfl_xor(s, 1);
      s += __shfl_xor(s, 2);
      s += __shfl_xor(s, 4);
      s += __shfl_xor(s, 8);
      lg2il[mt][r] = -__log2f(s);
    }

  // ---- pass 2: K double-buffered across tiles (loads always older than stores) ----
  f32x4 octx[2][4];
  for (int mt = 0; mt < 2; ++mt)
    for (int nt = 0; nt < 4; ++nt) octx[mt][nt] = (f32x4){0.f, 0.f, 0.f, 0.f};

  {
    bf16x8 kfA[2][4], kfB[2][4];
    LOADK(kfA, 0);
    for (int kb = 0; kb < nkb; kb += 2) {
      P2TILE(kfA, kfB, kb, 1);                       // kb+1 < nkb (nkb even)
      P2TILE(kfB, kfA, kb + 1, (kb + 2) < nkb);
    }
  }

  // zero-fill fully-masked future columns (reference softmax gives exactly 0)
  int jz = nkb * KBLK;
  int ncol4 = (S_LEN - jz) >> 2;
  if (ncol4 > 0) {
    f32x4 z = (f32x4){0.f, 0.f, 0.f, 0.f};
    for (int rr = 0; rr < QBLK; ++rr) {
      float* prow = Pg + (size_t)(q0 + rr) * S_LEN + jz;
      for (int j4 = tid; j4 < ncol4; j4 += 256)
        __builtin_nontemporal_store(z, (f32x4*)(prow + j4 * 4));
    }
  }

  // write context bf16 [8192][1024] (row = b*S+s, col = h*64+d)
  int b = bh >> 4, h = bh & 15;
  for (int mt = 0; mt < 2; ++mt)
    for (int nt = 0; nt < 4; ++nt)
      for (int r = 0; r < 4; ++r) {
        int rl = w * 32 + mt * 16 + lg * 4 + r;
        int d = nt * 16 + ln;
        ctx[((size_t)(b * S_LEN + q0 + rl)) * DMODEL + h * DH + d] =
            f2bf(octx[mt][nt][r]);
      }
}

extern "C" void kernel_launch(void* const* d_in, const int* in_sizes, int n_in,
                              void* d_out, int out_size, void* d_ws, size_t ws_size,
                              hipStream_t stream) {
  (void)in_sizes; (void)n_in; (void)out_size; (void)ws_size;
  const float* x  = (const float*)d_in[0];
  // d_in[1] = attn_mask (static causal; not needed)
  const float* Wq = (const float*)d_in[2];
  const float* bq = (const float*)d_in[3];
  const float* Wk = (const float*)d_in[4];
  const float* bk = (const float*)d_in[5];
  const float* Wv = (const float*)d_in[6];
  const float* bv = (const float*)d_in[7];
  const float* Wo = (const float*)d_in[8];
  const float* bo = (const float*)d_in[9];

  char* ws = (char*)d_ws;
  u16* xb   = (u16*)(ws);                                  // 16 MB
  u16* Wcat = (u16*)(ws + 16777216);                       // WqT|WkT|WvT|WoT, 2 MB each
  u16* WoT  = Wcat + 3 * (size_t)DMODEL * DMODEL;
  u16* Qh   = (u16*)(ws + 25165824);                       // 16 MB each
  u16* Kh   = (u16*)(ws + 25165824 + 1 * 16777216);
  u16* ctx  = (u16*)(ws + 25165824 + 2 * 16777216);
  u16* Vt   = (u16*)(ws + 25165824 + 3 * 16777216);

  float* outp = (float*)d_out;
  float* Pg = outp + (size_t)BATCH * S_LEN * DMODEL;

  k_prep<<<dim3(8192), 256, 0, stream>>>(x, xb, Wq, Wk, Wv, Wo, Wcat);
  k_gemm_qkv<<<dim3(1536), 256, 0, stream>>>(xb, Wcat, bq, bk, bv, Qh, Kh, Vt);
  k_attn<<<dim3(1024), 256, 0, stream>>>(Qh, Kh, Vt, Pg, ctx);
  k_gemm_out<<<dim3(512), 256, 0, stream>>>(ctx, WoT, bo, outp);
}